// Round 5
// baseline (1904.244 us; speedup 1.0000x reference)
//
#include <hip/hip_runtime.h>

// 2-layer LSTM (H=32, D=10, T=512), layer-pipelined:
// threads   0..127: layer-1 gate for timestep k
// threads 128..255: layer-2 gate for timestep k-1 (software wavefront)
// Weights held as named float2 values fed to inline-asm v_pk_fma_f32
// (VOP3P: 2 fp32 FMA / instruction). Asm operands force architectural-VGPR
// residency; one asm-volatile pin after load prevents remat/sinking.
// Gate exchange via __shfl_down (no LDS array, no memory clobber).

#define HH 32
#define DD 10
#define TT 512

typedef __attribute__((ext_vector_type(2))) float f2;

__device__ __forceinline__ f2 pk(f2 w, f2 v, f2 acc) {
    asm("v_pk_fma_f32 %0, %1, %2, %0" : "+v"(acc) : "v"(w), "v"(v));
    return acc;
}

__device__ __forceinline__ float fast_sigmoid(float v) {
    float e = __expf(-v);
    return __builtin_amdgcn_rcpf(1.0f + e);
}
__device__ __forceinline__ float fast_tanh(float v) {
    return fmaf(2.0f, fast_sigmoid(2.0f * v), -1.0f);
}

#define DECL16(W) f2 W##0,W##1,W##2,W##3,W##4,W##5,W##6,W##7, \
                     W##8,W##9,W##10,W##11,W##12,W##13,W##14,W##15;
#define LDW16(W, P) do { \
    W##0 =(P)[0];  W##1 =(P)[1];  W##2 =(P)[2];  W##3 =(P)[3];  \
    W##4 =(P)[4];  W##5 =(P)[5];  W##6 =(P)[6];  W##7 =(P)[7];  \
    W##8 =(P)[8];  W##9 =(P)[9];  W##10=(P)[10]; W##11=(P)[11]; \
    W##12=(P)[12]; W##13=(P)[13]; W##14=(P)[14]; W##15=(P)[15]; \
} while (0)
#define PIN16(W) do { \
    asm volatile("" : "+v"(W##0),"+v"(W##1),"+v"(W##2),"+v"(W##3), \
                      "+v"(W##4),"+v"(W##5),"+v"(W##6),"+v"(W##7)); \
    asm volatile("" : "+v"(W##8),"+v"(W##9),"+v"(W##10),"+v"(W##11), \
                      "+v"(W##12),"+v"(W##13),"+v"(W##14),"+v"(W##15)); \
} while (0)
#define DOT16(W, P) do { \
    aa = pk(W##0 , (P)[0] , aa); ab = pk(W##1 , (P)[1] , ab); \
    aa = pk(W##2 , (P)[2] , aa); ab = pk(W##3 , (P)[3] , ab); \
    aa = pk(W##4 , (P)[4] , aa); ab = pk(W##5 , (P)[5] , ab); \
    aa = pk(W##6 , (P)[6] , aa); ab = pk(W##7 , (P)[7] , ab); \
    aa = pk(W##8 , (P)[8] , aa); ab = pk(W##9 , (P)[9] , ab); \
    aa = pk(W##10, (P)[10], aa); ab = pk(W##11, (P)[11], ab); \
    aa = pk(W##12, (P)[12], aa); ab = pk(W##13, (P)[13], ab); \
    aa = pk(W##14, (P)[14], aa); ab = pk(W##15, (P)[15], ab); \
} while (0)

__global__ __launch_bounds__(256, 2) void lstm2_pkasm(
    const float* __restrict__ x,
    const float* __restrict__ Wih0, const float* __restrict__ Whh0,
    const float* __restrict__ bih0, const float* __restrict__ bhh0,
    const float* __restrict__ Wih1, const float* __restrict__ Whh1,
    const float* __restrict__ bih1, const float* __restrict__ bhh1,
    const float* __restrict__ Wfc,  const float* __restrict__ bfc,
    float* __restrict__ out)
{
    __shared__ __align__(16) float xs[TT * DD];     // 20480 B
    __shared__ __align__(16) float h1buf[2][HH];
    __shared__ __align__(16) float h2buf[2][HH];

    const int tid  = threadIdx.x;
    const bool isL1 = tid < 128;
    const int tl   = tid & 127;
    const int j    = tl >> 2;          // hidden unit
    const int q    = tl & 3;           // 0=i 1=f 2=g(tanh) 3=o
    const int row  = q * HH + j;       // row in [4H, *] weight layout

    // ---- stage this batch's x into LDS (coalesced float4) ----
    {
        const float4* src = (const float4*)(x + (size_t)blockIdx.x * TT * DD);
        float4* dst = (float4*)xs;
        #pragma unroll
        for (int i = 0; i < 5; i++) dst[tid + 256 * i] = src[tid + 256 * i];
    }

    // ---- weights as named f2 values ----
    // WH multiplies h1(k-1) in BOTH roles.
    // WA: L1 -> x weights in WA0..WA4 (rest zero); L2 -> h2-recurrent weights.
    DECL16(WH)
    DECL16(WA)
    float bb;
    if (isL1) {
        const f2* wh = (const f2*)(Whh0 + row * HH);
        LDW16(WH, wh);
        const f2* wx = (const f2*)(Wih0 + row * DD);
        WA0 = wx[0]; WA1 = wx[1]; WA2 = wx[2]; WA3 = wx[3]; WA4 = wx[4];
        WA5=WA6=WA7=WA8=WA9=WA10=WA11=WA12=WA13=WA14=WA15=(f2)(0.0f);
        bb = bih0[row] + bhh0[row];
    } else {
        const f2* wh = (const f2*)(Wih1 + row * HH);   // multiplies h1 input
        LDW16(WH, wh);
        const f2* wa = (const f2*)(Whh1 + row * HH);   // multiplies h2 recur
        LDW16(WA, wa);
        bb = bih1[row] + bhh1[row];
    }
    PIN16(WH);
    PIN16(WA);
    asm volatile("" : "+v"(bb));

    // activation: act(v) = sB * sigmoid(sA*v) + sC   (tanh when q==2)
    const bool is_t = (q == 2);
    const float sA = is_t ? 2.0f : 1.0f;
    const float sB = is_t ? 2.0f : 1.0f;
    const float sC = is_t ? -1.0f : 0.0f;

    if (tid < 64)       (&h1buf[0][0])[tid]      = 0.0f;
    else if (tid < 128) (&h2buf[0][0])[tid - 64] = 0.0f;

    float c = 0.0f;
    __syncthreads();

    for (int k = 0; k <= TT; ++k) {
        const int pr = k & 1;
        const bool active = isL1 ? (k < TT) : (k > 0);
        if (active) {
            f2 aa = {bb, 0.0f};
            f2 ab = {0.0f, 0.0f};
            if (isL1) {
                const f2* xp = (const f2*)&xs[k * DD];      // 8B aligned, bcast
                aa = pk(WA0, xp[0], aa); ab = pk(WA1, xp[1], ab);
                aa = pk(WA2, xp[2], aa); ab = pk(WA3, xp[3], ab);
                aa = pk(WA4, xp[4], aa);
            } else {
                const f2* h2p = (const f2*)&h2buf[pr][0];   // h2(k-2), bcast
                DOT16(WA, h2p);
            }
            const f2* h1p = (const f2*)&h1buf[pr ^ 1][0];   // h1(k-1), bcast
            DOT16(WH, h1p);
            float s = (aa.x + ab.x) + (aa.y + ab.y);
            float a = fmaf(sB, fast_sigmoid(sA * s), sC);   // activated gate

            // gate exchange within lane-quad: 4j:i  4j+1:f  4j+2:g~  4j+3:o
            float f_ = __shfl_down(a, 1);
            float g_ = __shfl_down(a, 2);
            float o_ = __shfl_down(a, 3);
            if (q == 0) {
                c = fmaf(f_, c, a * g_);
                float h = o_ * fast_tanh(c);
                if (isL1) h1buf[pr][j]     = h;   // h1(k)   @ parity k&1
                else      h2buf[pr ^ 1][j] = h;   // h2(k-1) @ parity (k-1)&1
            }
        }
        __syncthreads();
    }

    // ---- final FC on h2(T-1) (parity (T-1)&1 == 1) ----
    if (tid == 0) {
        float v = bfc[0];
        #pragma unroll
        for (int m = 0; m < HH; ++m) v = fmaf(h2buf[1][m], Wfc[m], v);
        out[blockIdx.x] = v;
    }
}

extern "C" void kernel_launch(void* const* d_in, const int* in_sizes, int n_in,
                              void* d_out, int out_size, void* d_ws, size_t ws_size,
                              hipStream_t stream) {
    const float* x    = (const float*)d_in[0];
    const float* Wih0 = (const float*)d_in[1];
    const float* Whh0 = (const float*)d_in[2];
    const float* bih0 = (const float*)d_in[3];
    const float* bhh0 = (const float*)d_in[4];
    const float* Wih1 = (const float*)d_in[5];
    const float* Whh1 = (const float*)d_in[6];
    const float* bih1 = (const float*)d_in[7];
    const float* bhh1 = (const float*)d_in[8];
    const float* Wfc  = (const float*)d_in[9];
    const float* bfc  = (const float*)d_in[10];
    float* out = (float*)d_out;

    const int B = in_sizes[0] / (TT * DD);   // 4096
    dim3 grid(B), block(256);
    hipLaunchKernelGGL(lstm2_pkasm, grid, block, 0, stream,
                       x, Wih0, Whh0, bih0, bhh0,
                       Wih1, Whh1, bih1, bhh1, Wfc, bfc, out);
}

// Round 7
// 928.019 us; speedup vs baseline: 2.0519x; 2.0519x over previous
//
#include <hip/hip_runtime.h>

// 2-layer LSTM (H=32, D=10, T=512) via MFMA split-bf16 (fp32-accurate).
// Per step, per layer: gates^T[128 x 16batch] = Wcat[128 x 64] @ cat[64 x 16].
// mfma_f32_16x16x32_bf16: D col = lane&15 = batch, D row = (lane>>4)*4+reg =
// gate (m89-verified). A-frags (weights) built once, hi/lo split, ~128 VGPRs;
// if the allocator parks them in AGPRs, mfma reads AGPRs natively (no tax).
// fp32 accuracy via 3-term split: Ah*Bh + Ah*Bl + Al*Bh (residual ~2^-18).
// wave0 = layer1 (step k), wave1 = layer2 (step k-1), 1 barrier/step.
// h exchanged through parity-double-buffered cat-layout LDS buffers.
// log2(e) (x2 for g-gate rows) folded into weights+bias: act = rcp(1+exp2(-s)).

#define HH 32
#define DD 10
#define TT 512
#define CH 64              // x-chunk (timesteps staged in LDS at a time)
#define NB 16              // batches per block
#define L2E 1.44269504088896340736f

typedef __attribute__((ext_vector_type(4))) float f32x4;
typedef __attribute__((ext_vector_type(8))) short bf16x8;
typedef __attribute__((ext_vector_type(2))) float f2;

__device__ __forceinline__ short bfhi(float x, float& rem) {
    unsigned u = __float_as_uint(x);
    unsigned short h = (unsigned short)((u + 0x8000u) >> 16);   // RN-ish hi
    rem = x - __uint_as_float(((unsigned)h) << 16);             // exact residual
    return (short)h;
}
__device__ __forceinline__ short bfrd(float x) {
    return (short)(unsigned short)((__float_as_uint(x) + 0x8000u) >> 16);
}
__device__ __forceinline__ float sig2(float v) {   // 1/(1+2^-v); v pre-scaled
    return __builtin_amdgcn_rcpf(1.0f + exp2f(-v));
}

__global__ __launch_bounds__(128, 1) void lstm2_mfma(
    const float* __restrict__ x,
    const float* __restrict__ Wih0, const float* __restrict__ Whh0,
    const float* __restrict__ bih0, const float* __restrict__ bhh0,
    const float* __restrict__ Wih1, const float* __restrict__ Whh1,
    const float* __restrict__ bih1, const float* __restrict__ bhh1,
    const float* __restrict__ Wfc,  const float* __restrict__ bfc,
    float* __restrict__ out)
{
    __shared__ __align__(16) float xs[CH][NB][12];   // 48 KB, x chunk (padded)
    __shared__ __align__(16) float h1x[2][64][17];   // L1 cat: [x10|z6|h1 32|z16]
    __shared__ __align__(16) float c2s[2][64][17];   // L2 cat: [h1 32|h2 32]
    __shared__ __align__(16) float b1L[128], b2L[128];

    const int tid  = threadIdx.x;
    const bool isL2 = tid >= 64;
    const int lane = tid & 63;
    const int b    = lane & 15;      // batch column (B-frag) / row-local (A-frag)
    const int g4   = lane >> 4;      // k-slot group
    const int b0   = blockIdx.x * NB;

    // zero cat buffers (both parities; pad rows stay 0 forever)
    for (int i = tid; i < 2 * 64 * 17; i += 128) {
        (&h1x[0][0][0])[i] = 0.0f;
        (&c2s[0][0][0])[i] = 0.0f;
    }
    {   // biases, pre-scaled
        const int r = tid & 127;
        const float sc = L2E * ((r >= 64 && r < 96) ? 2.0f : 1.0f);
        if (tid < 128) {
            b1L[r] = (bih0[r] + bhh0[r]) * sc;
            b2L[r] = (bih1[r] + bhh1[r]) * sc;
        }
    }

    // ---- A-fragments: Wcat[128 x 64], scaled, split hi/lo ----
    // A k-slot: k = 32*kt + 8*g4 + e ; A row (this M-tile) = 16*m + (lane&15).
    bf16x8 Ah[8][2], Al[8][2];
    {
        #pragma unroll
        for (int m = 0; m < 8; ++m) {
            const int row = 16 * m + b;
            const float sc = L2E * ((row >= 64 && row < 96) ? 2.0f : 1.0f);
            #pragma unroll
            for (int kt = 0; kt < 2; ++kt) {
                bf16x8 hi, lo;
                #pragma unroll
                for (int e = 0; e < 8; ++e) {
                    const int k = 32 * kt + 8 * g4 + e;
                    float w;
                    if (!isL2) {   // L1 cat: [x(10) z(6) | h1(32) | z(16)]
                        if (k < DD)                 w = Wih0[row * DD + k];
                        else if (k >= 16 && k < 48) w = Whh0[row * HH + (k - 16)];
                        else                        w = 0.0f;
                    } else {       // L2 cat: [h1(32) | h2(32)]
                        w = (k < HH) ? Wih1[row * HH + k]
                                     : Whh1[row * HH + (k - HH)];
                    }
                    w *= sc;
                    float rem;
                    hi[e] = bfhi(w, rem);
                    lo[e] = bfrd(rem);
                }
                Ah[m][kt] = hi;
                Al[m][kt] = lo;
            }
        }
    }

    float cst[2][4] = {{0.f,0.f,0.f,0.f},{0.f,0.f,0.f,0.f}};   // cell state
    __syncthreads();

    for (int kk = 0; kk <= TT; ++kk) {
        const int pr = kk & 1;

        if ((kk & (CH - 1)) == 0 && kk < TT) {   // stage x[kk, kk+CH)
            #pragma unroll
            for (int p = 0; p < 8; ++p) {
                const int idx = tid + 128 * p;
                const int tt = idx >> 4, bb = idx & 15;
                const float* src = x + (size_t)(b0 + bb) * (TT * DD)
                                     + (size_t)(kk + tt) * DD;
                f2 v0 = *(const f2*)(src);     f2 v1 = *(const f2*)(src + 2);
                f2 v2 = *(const f2*)(src + 4); f2 v3 = *(const f2*)(src + 6);
                f2 v4 = *(const f2*)(src + 8);
                f2* dst = (f2*)&xs[tt][bb][0];
                f2 zz; zz.x = 0.0f; zz.y = 0.0f;
                dst[0] = v0; dst[1] = v1; dst[2] = v2; dst[3] = v3; dst[4] = v4;
                dst[5] = zz;   // pad floats 10,11
            }
            __syncthreads();
        }

        const bool active = isL2 ? (kk > 0) : (kk < TT);
        if (active) {
            if (!isL2) {   // copy x(kk) into cat rows 0..11 of the READ buffer
                const int tc = kk & (CH - 1);
                #pragma unroll
                for (int p = 0; p < 3; ++p) {
                    const int d = 4 * p + g4;            // 0..11 (10,11 = 0)
                    h1x[pr ^ 1][d][b] = xs[tc][b][d];
                }
            }
            const float (*cat)[17] = isL2 ? c2s[pr ^ 1] : h1x[pr ^ 1];

            // B-frag: col = batch = lane&15, k-slot = 32*kt + 8*g4 + e
            float raw0[8], raw1[8];
            #pragma unroll
            for (int e = 0; e < 8; ++e) {
                raw0[e] = cat[8 * g4 + e][b];
                raw1[e] = cat[32 + 8 * g4 + e][b];
            }
            bf16x8 Bh0, Bl0, Bh1, Bl1;
            #pragma unroll
            for (int e = 0; e < 8; ++e) {
                float r0, r1;
                Bh0[e] = bfhi(raw0[e], r0); Bl0[e] = bfrd(r0);
                Bh1[e] = bfhi(raw1[e], r1); Bl1[e] = bfrd(r1);
            }

            const float* bL = isL2 ? b2L : b1L;
            f32x4 acc[8];
            #pragma unroll
            for (int m = 0; m < 8; ++m) {
                acc[m] = *(const f32x4*)&bL[16 * m + 4 * g4];
                acc[m] = __builtin_amdgcn_mfma_f32_16x16x32_bf16(Ah[m][0], Bh0, acc[m], 0, 0, 0);
                acc[m] = __builtin_amdgcn_mfma_f32_16x16x32_bf16(Ah[m][0], Bl0, acc[m], 0, 0, 0);
                acc[m] = __builtin_amdgcn_mfma_f32_16x16x32_bf16(Al[m][0], Bh0, acc[m], 0, 0, 0);
                acc[m] = __builtin_amdgcn_mfma_f32_16x16x32_bf16(Ah[m][1], Bh1, acc[m], 0, 0, 0);
                acc[m] = __builtin_amdgcn_mfma_f32_16x16x32_bf16(Ah[m][1], Bl1, acc[m], 0, 0, 0);
                acc[m] = __builtin_amdgcn_mfma_f32_16x16x32_bf16(Al[m][1], Bh1, acc[m], 0, 0, 0);
            }

            // gate G = 16m + 4*g4 + reg; i:m0,1  f:m2,3  g:m4,5  o:m6,7
            #pragma unroll
            for (int mi = 0; mi < 2; ++mi) {
                #pragma unroll
                for (int r = 0; r < 4; ++r) {
                    const float iv = acc[mi][r],     fv = acc[mi + 2][r];
                    const float gv = acc[mi + 4][r], ov = acc[mi + 6][r];
                    const float gt = fmaf(2.0f, sig2(gv), -1.0f);      // tanh(g)
                    const float cn = fmaf(sig2(fv), cst[mi][r], sig2(iv) * gt);
                    cst[mi][r] = cn;
                    const float h =
                        sig2(ov) * fmaf(2.0f, sig2(2.0f * L2E * cn), -1.0f);
                    const int u = 16 * mi + 4 * g4 + r;   // hidden unit
                    if (!isL2) {
                        h1x[pr][16 + u][b] = h;   // L1 cat (own next input)
                        c2s[pr][u][b]      = h;   // L2 cat rows 0..31
                    } else {
                        c2s[pr][32 + u][b] = h;   // L2 cat rows 32..63
                    }
                }
            }
        }
        __syncthreads();
    }

    // final FC on h2(511): written at iter kk=512 (pr=0) -> c2s[0][32+u][b]
    if (tid < NB) {
        float v = bfc[0];
        #pragma unroll
        for (int u = 0; u < HH; ++u)
            v = fmaf(c2s[0][32 + u][tid], Wfc[u], v);
        out[b0 + tid] = v;
    }
}

extern "C" void kernel_launch(void* const* d_in, const int* in_sizes, int n_in,
                              void* d_out, int out_size, void* d_ws, size_t ws_size,
                              hipStream_t stream) {
    const float* x    = (const float*)d_in[0];
    const float* Wih0 = (const float*)d_in[1];
    const float* Whh0 = (const float*)d_in[2];
    const float* bih0 = (const float*)d_in[3];
    const float* bhh0 = (const float*)d_in[4];
    const float* Wih1 = (const float*)d_in[5];
    const float* Whh1 = (const float*)d_in[6];
    const float* bih1 = (const float*)d_in[7];
    const float* bhh1 = (const float*)d_in[8];
    const float* Wfc  = (const float*)d_in[9];
    const float* bfc  = (const float*)d_in[10];
    float* out = (float*)d_out;

    const int B = in_sizes[0] / (TT * DD);   // 4096
    dim3 grid(B / NB), block(128);           // 256 blocks x 2 waves
    hipLaunchKernelGGL(lstm2_mfma, grid, block, 0, stream,
                       x, Wih0, Whh0, bih0, bhh0,
                       Wih1, Whh1, bih1, bhh1, Wfc, bfc, out);
}

// Round 8
// 735.547 us; speedup vs baseline: 2.5889x; 1.2617x over previous
//
#include <hip/hip_runtime.h>

// 2-layer LSTM (H=32, D=10, T=512) via MFMA split-bf16, producer-side split.
// wave0 = layer1 (step k), wave1 = layer2 (step k-1); 1 barrier/step.
// h-state stored in LDS as bf16 (hi,lo) TRANSPOSED [batch][k] with padded
// strides: a consumer B-frag k-slice = one aligned ds_read_b128 (2-way bank
// aliasing = free). x pre-split to bf16 hi/lo at chunk staging (every CH
// steps). L1 cat k-order: [h1(32) | x(10)+pad]. 3-term split MFMA
// (AhBh+AhBl+AlBh) = fp32-accurate (round-6 verified, absmax 0).

#define HH 32
#define DD 10
#define TT 512
#define CH 32              // x timesteps staged per chunk
#define NB 16              // batches per block
#define XPS 776            // x plane stride per batch (shorts) = 32*24+8
#define XRS 24             // x row stride per timestep (shorts)
#define RS  40             // h row stride per batch (shorts)
#define L2E 1.44269504088896340736f

typedef __attribute__((ext_vector_type(4))) float f32x4;
typedef __attribute__((ext_vector_type(8))) short bf16x8;
typedef __attribute__((ext_vector_type(4))) short bf16x4;
typedef __attribute__((ext_vector_type(2))) float f2;

__device__ __forceinline__ short bfhi(float x, float& rem) {
    unsigned u = __float_as_uint(x);
    unsigned short h = (unsigned short)((u + 0x8000u) >> 16);
    rem = x - __uint_as_float(((unsigned)h) << 16);   // exact residual
    return (short)h;
}
__device__ __forceinline__ short bfrd(float x) {
    return (short)(unsigned short)((__float_as_uint(x) + 0x8000u) >> 16);
}
__device__ __forceinline__ float sig2(float v) {   // 1/(1+2^-v), v pre-scaled
    return __builtin_amdgcn_rcpf(1.0f + exp2f(-v));
}

__global__ __launch_bounds__(128, 1) void lstm2_mfma2(
    const float* __restrict__ x,
    const float* __restrict__ Wih0, const float* __restrict__ Whh0,
    const float* __restrict__ bih0, const float* __restrict__ bhh0,
    const float* __restrict__ Wih1, const float* __restrict__ Whh1,
    const float* __restrict__ bih1, const float* __restrict__ bhh1,
    const float* __restrict__ Wfc,  const float* __restrict__ bfc,
    float* __restrict__ out)
{
    __shared__ __align__(16) short xh[NB * XPS];      // 24.3 KB  x hi
    __shared__ __align__(16) short xl[NB * XPS];      // 24.3 KB  x lo
    __shared__ __align__(16) short hb[4][2][NB][RS];  // 10 KB: bh1,bl1,bh2,bl2
    __shared__ __align__(16) float b1L[128], b2L[128];

    const int tid  = threadIdx.x;
    const bool isL2 = tid >= 64;
    const int lane = tid & 63;
    const int b    = lane & 15;      // batch col (B/D frag) / row-local (A)
    const int g4   = lane >> 4;      // k-slot group
    const int b0   = blockIdx.x * NB;

    // zero h-state (both parities)
    for (int i = tid; i < (int)(sizeof(hb) / 4); i += 128) ((int*)hb)[i] = 0;
    {   // biases, pre-scaled by log2e (x2 for g rows)
        const float sc = L2E * ((tid >= 64 && tid < 96) ? 2.0f : 1.0f);
        b1L[tid] = (bih0[tid] + bhh0[tid]) * sc;
        b2L[tid] = (bih1[tid] + bhh1[tid]) * sc;
    }

    // ---- A-fragments, hi/lo split. A row = 16m + (lane&15), k = 32kt+8g4+e.
    // L1 cat: kt0 = h1 (Whh0), kt1 = x (Wih0, k<10) else 0.
    // L2 cat: kt0 = h1 (Wih1), kt1 = h2 (Whh1).
    bf16x8 Ah[8][2], Al[8][2];
    #pragma unroll
    for (int m = 0; m < 8; ++m) {
        const int row = 16 * m + b;
        const float sc = L2E * ((row >= 64 && row < 96) ? 2.0f : 1.0f);
        #pragma unroll
        for (int kt = 0; kt < 2; ++kt) {
            bf16x8 hi, lo;
            #pragma unroll
            for (int e = 0; e < 8; ++e) {
                const int k = 8 * g4 + e;   // k within tile
                float w;
                if (!isL2) w = (kt == 0) ? Whh0[row * HH + k]
                                         : ((k < DD) ? Wih0[row * DD + k] : 0.0f);
                else       w = (kt == 0) ? Wih1[row * HH + k]
                                         : Whh1[row * HH + k];
                w *= sc;
                float rem;
                hi[e] = bfhi(w, rem);
                lo[e] = bfrd(rem);
            }
            Ah[m][kt] = hi;
            Al[m][kt] = lo;
        }
    }

    float cst[2][4] = {{0.f,0.f,0.f,0.f},{0.f,0.f,0.f,0.f}};
    __syncthreads();

    for (int kk = 0; kk <= TT; ++kk) {
        const int pr = kk & 1;

        // ---- stage + pre-split x chunk (coalesced; every CH steps) ----
        if ((kk & (CH - 1)) == 0 && kk < TT) {
            #pragma unroll
            for (int p = 0; p < (CH * NB) / 128; ++p) {
                const int idx = tid + 128 * p;
                const int t = idx & (CH - 1), bb = idx >> 5;
                const f2* sp = (const f2*)(x + (size_t)(b0 + bb) * (TT * DD)
                                             + (size_t)(kk + t) * DD);
                f2 v0 = sp[0], v1 = sp[1], v2 = sp[2], v3 = sp[3], v4 = sp[4];
                const float av[10] = {v0.x, v0.y, v1.x, v1.y, v2.x,
                                      v2.y, v3.x, v3.y, v4.x, v4.y};
                short th[16], tl[16];
                #pragma unroll
                for (int d = 0; d < DD; ++d) {
                    float rem;
                    th[d] = bfhi(av[d], rem);
                    tl[d] = bfrd(rem);
                }
                #pragma unroll
                for (int d = DD; d < 16; ++d) { th[d] = 0; tl[d] = 0; }
                short* ph = &xh[bb * XPS + t * XRS];
                short* pl = &xl[bb * XPS + t * XRS];
                *(bf16x8*)(ph)     = bf16x8{th[0],th[1],th[2],th[3],th[4],th[5],th[6],th[7]};
                *(bf16x8*)(ph + 8) = bf16x8{th[8],th[9],th[10],th[11],th[12],th[13],th[14],th[15]};
                *(bf16x8*)(pl)     = bf16x8{tl[0],tl[1],tl[2],tl[3],tl[4],tl[5],tl[6],tl[7]};
                *(bf16x8*)(pl + 8) = bf16x8{tl[8],tl[9],tl[10],tl[11],tl[12],tl[13],tl[14],tl[15]};
            }
            __syncthreads();
        }

        const bool active = isL2 ? (kk > 0) : (kk < TT);
        if (active) {
            // ---- B-frags: one ds_read_b128 per (array, k-tile) ----
            bf16x8 Bh0, Bl0;
            bf16x8 Bh1 = {0,0,0,0,0,0,0,0}, Bl1 = {0,0,0,0,0,0,0,0};
            Bh0 = *(const bf16x8*)&hb[0][pr ^ 1][b][8 * g4];   // h1(prev) hi
            Bl0 = *(const bf16x8*)&hb[1][pr ^ 1][b][8 * g4];   // h1(prev) lo
            if (!isL2) {
                if (g4 < 2) {   // x occupies k-tile1 slots 0..15
                    const int tc = kk & (CH - 1);
                    Bh1 = *(const bf16x8*)&xh[b * XPS + tc * XRS + 8 * g4];
                    Bl1 = *(const bf16x8*)&xl[b * XPS + tc * XRS + 8 * g4];
                }
            } else {
                Bh1 = *(const bf16x8*)&hb[2][pr][b][8 * g4];   // h2(k-2) hi
                Bl1 = *(const bf16x8*)&hb[3][pr][b][8 * g4];   // h2(k-2) lo
            }

            const float* bL = isL2 ? b2L : b1L;
            f32x4 acc[8];
            #pragma unroll
            for (int m = 0; m < 8; ++m) {
                acc[m] = *(const f32x4*)&bL[16 * m + 4 * g4];   // broadcast
                acc[m] = __builtin_amdgcn_mfma_f32_16x16x32_bf16(Ah[m][0], Bh0, acc[m], 0, 0, 0);
                acc[m] = __builtin_amdgcn_mfma_f32_16x16x32_bf16(Ah[m][0], Bl0, acc[m], 0, 0, 0);
                acc[m] = __builtin_amdgcn_mfma_f32_16x16x32_bf16(Al[m][0], Bh0, acc[m], 0, 0, 0);
                acc[m] = __builtin_amdgcn_mfma_f32_16x16x32_bf16(Ah[m][1], Bh1, acc[m], 0, 0, 0);
                acc[m] = __builtin_amdgcn_mfma_f32_16x16x32_bf16(Ah[m][1], Bl1, acc[m], 0, 0, 0);
                acc[m] = __builtin_amdgcn_mfma_f32_16x16x32_bf16(Al[m][1], Bh1, acc[m], 0, 0, 0);
            }

            // ---- activation: gate rows i:m0,1 f:m2,3 g:m4,5 o:m6,7 ----
            short hh[2][4], hl[2][4];
            #pragma unroll
            for (int mi = 0; mi < 2; ++mi) {
                #pragma unroll
                for (int r = 0; r < 4; ++r) {
                    const float iv = acc[mi][r],     fv = acc[mi + 2][r];
                    const float gv = acc[mi + 4][r], ov = acc[mi + 6][r];
                    const float gt = fmaf(2.0f, sig2(gv), -1.0f);      // tanh g
                    const float cn = fmaf(sig2(fv), cst[mi][r], sig2(iv) * gt);
                    cst[mi][r] = cn;
                    const float h =
                        sig2(ov) * fmaf(2.0f, sig2(2.0f * L2E * cn), -1.0f);
                    float rem;
                    hh[mi][r] = bfhi(h, rem);
                    hl[mi][r] = bfrd(rem);
                }
            }
            // ---- producer writes: u = 16mi + 4g4 + r -> one b64 per (mi,arr)
            const int arr = isL2 ? 2 : 0;
            const int wp  = isL2 ? (pr ^ 1) : pr;   // parity of produced step
            short* bh = &hb[arr][wp][b][0];
            short* bl = &hb[arr + 1][wp][b][0];
            *(bf16x4*)&bh[4 * g4]      = bf16x4{hh[0][0], hh[0][1], hh[0][2], hh[0][3]};
            *(bf16x4*)&bh[16 + 4 * g4] = bf16x4{hh[1][0], hh[1][1], hh[1][2], hh[1][3]};
            *(bf16x4*)&bl[4 * g4]      = bf16x4{hl[0][0], hl[0][1], hl[0][2], hl[0][3]};
            *(bf16x4*)&bl[16 + 4 * g4] = bf16x4{hl[1][0], hl[1][1], hl[1][2], hl[1][3]};
        }
        __syncthreads();
    }

    // ---- final FC on h2(511): parity (511)&1 = 1 -> hb[2/3][1] ----
    if (tid < NB) {
        float v = bfc[0];
        #pragma unroll
        for (int u = 0; u < HH; ++u) {
            const unsigned hi = (unsigned short)hb[2][1][tid][u];
            const unsigned lo = (unsigned short)hb[3][1][tid][u];
            const float h = __uint_as_float(hi << 16) + __uint_as_float(lo << 16);
            v = fmaf(h, Wfc[u], v);
        }
        out[b0 + tid] = v;
    }
}

extern "C" void kernel_launch(void* const* d_in, const int* in_sizes, int n_in,
                              void* d_out, int out_size, void* d_ws, size_t ws_size,
                              hipStream_t stream) {
    const float* x    = (const float*)d_in[0];
    const float* Wih0 = (const float*)d_in[1];
    const float* Whh0 = (const float*)d_in[2];
    const float* bih0 = (const float*)d_in[3];
    const float* bhh0 = (const float*)d_in[4];
    const float* Wih1 = (const float*)d_in[5];
    const float* Whh1 = (const float*)d_in[6];
    const float* bih1 = (const float*)d_in[7];
    const float* bhh1 = (const float*)d_in[8];
    const float* Wfc  = (const float*)d_in[9];
    const float* bfc  = (const float*)d_in[10];
    float* out = (float*)d_out;

    const int B = in_sizes[0] / (TT * DD);   // 4096
    dim3 grid(B / NB), block(128);           // 256 blocks x 2 waves
    hipLaunchKernelGGL(lstm2_mfma2, grid, block, 0, stream,
                       x, Wih0, Whh0, bih0, bhh0,
                       Wih1, Whh1, bih1, bhh1, Wfc, bfc, out);
}

// Round 9
// 445.770 us; speedup vs baseline: 4.2718x; 1.6501x over previous
//
#include <hip/hip_runtime.h>

// 2-layer LSTM (H=32, D=10, T=512) via MFMA split-bf16, M-split 4-wave form.
// wave0 = L1 units 0-15 (M-tiles 0,2,4,6), wave1 = L1 units 16-31 (1,3,5,7),
// wave2 = L2 units 0-15, wave3 = L2 units 16-31.  L2 lags L1 by 1 step
// (software wavefront), one __syncthreads per step for the h1/h2 handoff.
// h-state in LDS as bf16 (hi,lo), transposed [batch][k]: consumer B-frag
// k-slice = one aligned ds_read_b128. x pre-split to bf16 hi/lo per chunk.
// 3-term split MFMA (AhBh+AhBl+AlBh) = fp32-accurate (r6/r7 verified).

#define HH 32
#define DD 10
#define TT 512
#define CH 32              // x timesteps staged per chunk
#define NB 16              // batches per block
#define XPS 776            // x plane stride per batch (shorts)
#define XRS 24             // x row stride per timestep (shorts)
#define RS  40             // h row stride per batch (shorts)
#define L2E 1.44269504088896340736f

typedef __attribute__((ext_vector_type(4))) float f32x4;
typedef __attribute__((ext_vector_type(8))) short bf16x8;
typedef __attribute__((ext_vector_type(4))) short bf16x4;
typedef __attribute__((ext_vector_type(2))) float f2;

__device__ __forceinline__ short bfhi(float x, float& rem) {
    unsigned u = __float_as_uint(x);
    unsigned short h = (unsigned short)((u + 0x8000u) >> 16);
    rem = x - __uint_as_float(((unsigned)h) << 16);   // exact residual
    return (short)h;
}
__device__ __forceinline__ short bfrd(float x) {
    return (short)(unsigned short)((__float_as_uint(x) + 0x8000u) >> 16);
}
__device__ __forceinline__ float sig2(float v) {   // 1/(1+2^-v), v pre-scaled
    return __builtin_amdgcn_rcpf(1.0f + exp2f(-v));
}

__global__ __launch_bounds__(256, 1) void lstm2_msplit(
    const float* __restrict__ x,
    const float* __restrict__ Wih0, const float* __restrict__ Whh0,
    const float* __restrict__ bih0, const float* __restrict__ bhh0,
    const float* __restrict__ Wih1, const float* __restrict__ Whh1,
    const float* __restrict__ bih1, const float* __restrict__ bhh1,
    const float* __restrict__ Wfc,  const float* __restrict__ bfc,
    float* __restrict__ out)
{
    __shared__ __align__(16) short xh[NB * XPS];      // 24.3 KB  x hi
    __shared__ __align__(16) short xl[NB * XPS];      // 24.3 KB  x lo
    __shared__ __align__(16) short hb[4][2][NB][RS];  // 10 KB: h1h,h1l,h2h,h2l
    __shared__ __align__(16) float b1L[128], b2L[128];

    const int tid  = threadIdx.x;
    const int wid  = tid >> 6;       // 0,1 = L1 halves; 2,3 = L2 halves
    const bool isL2 = wid >= 2;
    const int hf   = wid & 1;        // unit half: 0 -> units 0-15, 1 -> 16-31
    const int lane = tid & 63;
    const int b    = lane & 15;      // batch col (B/D) / row-local (A)
    const int g4   = lane >> 4;      // k-slot group
    const int b0   = blockIdx.x * NB;

    for (int i = tid; i < (int)(sizeof(hb) / 4); i += 256) ((int*)hb)[i] = 0;
    if (tid < 128) {   // biases, pre-scaled by log2e (x2 for g rows 64..95)
        const float sc = L2E * ((tid >= 64 && tid < 96) ? 2.0f : 1.0f);
        b1L[tid] = (bih0[tid] + bhh0[tid]) * sc;
        b2L[tid] = (bih1[tid] + bhh1[tid]) * sc;
    }

    // ---- A-fragments, hi/lo split; this wave's M-tiles m = 2j + hf ----
    // j = gate: 0=i 1=f 2=g 3=o.  row = 16m + b.  k = 8*g4 + e within k-tile.
    // L1: kt0 = Whh0 (h1 recur), kt1 = Wih0 (x, k<10 else 0).
    // L2: kt0 = Wih1 (h1 input), kt1 = Whh1 (h2 recur).
    bf16x8 Ah[4][2], Al[4][2];
    #pragma unroll
    for (int j = 0; j < 4; ++j) {
        const int m = 2 * j + hf;
        const int row = 16 * m + b;
        const float sc = L2E * ((j == 2) ? 2.0f : 1.0f);
        #pragma unroll
        for (int kt = 0; kt < 2; ++kt) {
            bf16x8 hi, lo;
            #pragma unroll
            for (int e = 0; e < 8; ++e) {
                const int k = 8 * g4 + e;
                float w;
                if (!isL2) w = (kt == 0) ? Whh0[row * HH + k]
                                         : ((k < DD) ? Wih0[row * DD + k] : 0.0f);
                else       w = (kt == 0) ? Wih1[row * HH + k]
                                         : Whh1[row * HH + k];
                w *= sc;
                float rem;
                hi[e] = bfhi(w, rem);
                lo[e] = bfrd(rem);
            }
            Ah[j][kt] = hi;
            Al[j][kt] = lo;
        }
    }

    float cst[4] = {0.f, 0.f, 0.f, 0.f};   // cell state, units 16hf+4g4+r
    __syncthreads();

    for (int kk = 0; kk <= TT; ++kk) {
        const int pr = kk & 1;

        // ---- stage + pre-split x chunk (every CH steps) ----
        if ((kk & (CH - 1)) == 0 && kk < TT) {
            #pragma unroll
            for (int p = 0; p < (CH * NB) / 256; ++p) {
                const int idx = tid + 256 * p;
                const int t = idx & (CH - 1), bb = idx >> 5;
                const f2* sp = (const f2*)(x + (size_t)(b0 + bb) * (TT * DD)
                                             + (size_t)(kk + t) * DD);
                f2 v0 = sp[0], v1 = sp[1], v2 = sp[2], v3 = sp[3], v4 = sp[4];
                const float av[10] = {v0.x, v0.y, v1.x, v1.y, v2.x,
                                      v2.y, v3.x, v3.y, v4.x, v4.y};
                short th[16], tl[16];
                #pragma unroll
                for (int d = 0; d < DD; ++d) {
                    float rem;
                    th[d] = bfhi(av[d], rem);
                    tl[d] = bfrd(rem);
                }
                #pragma unroll
                for (int d = DD; d < 16; ++d) { th[d] = 0; tl[d] = 0; }
                short* ph = &xh[bb * XPS + t * XRS];
                short* pl = &xl[bb * XPS + t * XRS];
                *(bf16x8*)(ph)     = bf16x8{th[0],th[1],th[2],th[3],th[4],th[5],th[6],th[7]};
                *(bf16x8*)(ph + 8) = bf16x8{th[8],th[9],th[10],th[11],th[12],th[13],th[14],th[15]};
                *(bf16x8*)(pl)     = bf16x8{tl[0],tl[1],tl[2],tl[3],tl[4],tl[5],tl[6],tl[7]};
                *(bf16x8*)(pl + 8) = bf16x8{tl[8],tl[9],tl[10],tl[11],tl[12],tl[13],tl[14],tl[15]};
            }
            __syncthreads();
        }

        const bool active = isL2 ? (kk > 0) : (kk < TT);
        if (active) {
            // ---- B-frags: one ds_read_b128 per (array, k-tile) ----
            bf16x8 Bh0, Bl0;
            bf16x8 Bh1 = {0,0,0,0,0,0,0,0}, Bl1 = {0,0,0,0,0,0,0,0};
            Bh0 = *(const bf16x8*)&hb[0][pr ^ 1][b][8 * g4];   // h1(prev) hi
            Bl0 = *(const bf16x8*)&hb[1][pr ^ 1][b][8 * g4];   // h1(prev) lo
            if (!isL2) {
                if (g4 < 2) {   // x occupies k-tile1 slots 0..15
                    const int tc = kk & (CH - 1);
                    Bh1 = *(const bf16x8*)&xh[b * XPS + tc * XRS + 8 * g4];
                    Bl1 = *(const bf16x8*)&xl[b * XPS + tc * XRS + 8 * g4];
                }
            } else {
                Bh1 = *(const bf16x8*)&hb[2][pr][b][8 * g4];   // h2(k-2) hi
                Bl1 = *(const bf16x8*)&hb[3][pr][b][8 * g4];   // h2(k-2) lo
            }

            const float* bL = isL2 ? b2L : b1L;
            f32x4 acc[4];
            #pragma unroll
            for (int j = 0; j < 4; ++j) {
                const int m = 2 * j + hf;
                acc[j] = *(const f32x4*)&bL[16 * m + 4 * g4];   // broadcast
                acc[j] = __builtin_amdgcn_mfma_f32_16x16x32_bf16(Ah[j][0], Bh0, acc[j], 0, 0, 0);
                acc[j] = __builtin_amdgcn_mfma_f32_16x16x32_bf16(Ah[j][0], Bl0, acc[j], 0, 0, 0);
                acc[j] = __builtin_amdgcn_mfma_f32_16x16x32_bf16(Al[j][0], Bh0, acc[j], 0, 0, 0);
                acc[j] = __builtin_amdgcn_mfma_f32_16x16x32_bf16(Ah[j][1], Bh1, acc[j], 0, 0, 0);
                acc[j] = __builtin_amdgcn_mfma_f32_16x16x32_bf16(Ah[j][1], Bl1, acc[j], 0, 0, 0);
                acc[j] = __builtin_amdgcn_mfma_f32_16x16x32_bf16(Al[j][1], Bh1, acc[j], 0, 0, 0);
            }

            // ---- activation: units u = 16hf + 4g4 + r (4 per lane) ----
            short hh[4], hl[4];
            #pragma unroll
            for (int r = 0; r < 4; ++r) {
                const float iv = acc[0][r], fv = acc[1][r];
                const float gv = acc[2][r], ov = acc[3][r];
                const float gt = fmaf(2.0f, sig2(gv), -1.0f);      // tanh(g)
                const float cn = fmaf(sig2(fv), cst[r], sig2(iv) * gt);
                cst[r] = cn;
                const float h =
                    sig2(ov) * fmaf(2.0f, sig2(2.0f * L2E * cn), -1.0f);
                float rem;
                hh[r] = bfhi(h, rem);
                hl[r] = bfrd(rem);
            }
            // ---- producer write: one b64 per array ----
            const int arr = isL2 ? 2 : 0;
            const int wp  = isL2 ? (pr ^ 1) : pr;   // parity of produced step
            *(bf16x4*)&hb[arr][wp][b][16 * hf + 4 * g4]     = bf16x4{hh[0], hh[1], hh[2], hh[3]};
            *(bf16x4*)&hb[arr + 1][wp][b][16 * hf + 4 * g4] = bf16x4{hl[0], hl[1], hl[2], hl[3]};
        }
        __syncthreads();
    }

    // ---- final FC on h2(511): parity 1 -> hb[2/3][1] ----
    if (tid < NB) {
        float v = bfc[0];
        #pragma unroll
        for (int u = 0; u < HH; ++u) {
            const unsigned hi = (unsigned short)hb[2][1][tid][u];
            const unsigned lo = (unsigned short)hb[3][1][tid][u];
            const float h = __uint_as_float(hi << 16) + __uint_as_float(lo << 16);
            v = fmaf(h, Wfc[u], v);
        }
        out[b0 + tid] = v;
    }
}

extern "C" void kernel_launch(void* const* d_in, const int* in_sizes, int n_in,
                              void* d_out, int out_size, void* d_ws, size_t ws_size,
                              hipStream_t stream) {
    const float* x    = (const float*)d_in[0];
    const float* Wih0 = (const float*)d_in[1];
    const float* Whh0 = (const float*)d_in[2];
    const float* bih0 = (const float*)d_in[3];
    const float* bhh0 = (const float*)d_in[4];
    const float* Wih1 = (const float*)d_in[5];
    const float* Whh1 = (const float*)d_in[6];
    const float* bih1 = (const float*)d_in[7];
    const float* bhh1 = (const float*)d_in[8];
    const float* Wfc  = (const float*)d_in[9];
    const float* bfc  = (const float*)d_in[10];
    float* out = (float*)d_out;

    const int B = in_sizes[0] / (TT * DD);   // 4096
    dim3 grid(B / NB), block(256);           // 256 blocks x 4 waves
    hipLaunchKernelGGL(lstm2_msplit, grid, block, 0, stream,
                       x, Wih0, Whh0, bih0, bhh0,
                       Wih1, Whh1, bih1, bhh1, Wfc, bfc, out);
}

// Round 11
// 438.898 us; speedup vs baseline: 4.3387x; 1.0157x over previous
//
#include <hip/hip_runtime.h>

// 2-layer LSTM (H=32, D=10, T=512), MFMA split-bf16, M-split 4-wave form.
// ROUND 10 = round-8 (PASSING) + {register bias, 2x3-deep builtin-MFMA
// chains, compile-time parity unroll-by-2, empty "+a" AGPR pin}.
// Deliberately NO inline-asm MFMA (r9's fail suspect: asm is opaque to the
// hazard recognizer -> missing MFMA wait-states). Builtin MFMA operands are
// AV-class (VGPR or AGPR) so AGPR-homed A-frags need no shuttle copies.
// wave0/1 = L1 unit-halves (step k), wave2/3 = L2 unit-halves (step k-1).
// h-state in LDS as bf16 (hi,lo) transposed [batch][k]; B-frag k-slice = one
// aligned ds_read_b128. 3-term split (AhBh+AhBl+AlBh) = fp32-accurate.

#define HH 32
#define DD 10
#define TT 512
#define CH 32              // x timesteps staged per chunk
#define NB 16              // batches per block
#define XPS 776            // x plane stride per batch (shorts)
#define XRS 24             // x row stride per timestep (shorts)
#define RS  40             // h row stride per batch (shorts)
#define L2E 1.44269504088896340736f

typedef __attribute__((ext_vector_type(4))) float f32x4;
typedef __attribute__((ext_vector_type(8))) short bf16x8;
typedef __attribute__((ext_vector_type(4))) short bf16x4;
typedef __attribute__((ext_vector_type(2))) float f2;

__device__ __forceinline__ short bfhi(float x, float& rem) {
    unsigned u = __float_as_uint(x);
    unsigned short h = (unsigned short)((u + 0x8000u) >> 16);
    rem = x - __uint_as_float(((unsigned)h) << 16);   // exact residual
    return (short)h;
}
__device__ __forceinline__ short bfrd(float x) {
    return (short)(unsigned short)((__float_as_uint(x) + 0x8000u) >> 16);
}
__device__ __forceinline__ float sig2(float v) {   // 1/(1+2^-v), v pre-scaled
    return __builtin_amdgcn_rcpf(1.0f + exp2f(-v));
}

__global__ __launch_bounds__(256, 1) void lstm2_r10(
    const float* __restrict__ x,
    const float* __restrict__ Wih0, const float* __restrict__ Whh0,
    const float* __restrict__ bih0, const float* __restrict__ bhh0,
    const float* __restrict__ Wih1, const float* __restrict__ Whh1,
    const float* __restrict__ bih1, const float* __restrict__ bhh1,
    const float* __restrict__ Wfc,  const float* __restrict__ bfc,
    float* __restrict__ out)
{
    __shared__ __align__(16) short xh[NB * XPS];      // 24.3 KB  x hi
    __shared__ __align__(16) short xl[NB * XPS];      // 24.3 KB  x lo
    __shared__ __align__(16) short hb[4][2][NB][RS];  // 10 KB: h1h,h1l,h2h,h2l

    const int tid  = threadIdx.x;
    const int wid  = tid >> 6;       // 0,1 = L1 halves; 2,3 = L2 halves
    const bool isL2 = wid >= 2;
    const int hf   = wid & 1;        // unit half: 0 -> units 0-15, 1 -> 16-31
    const int lane = tid & 63;
    const int b    = lane & 15;      // batch col (B/D) / row-local (A)
    const int g4   = lane >> 4;      // k-slot group
    const int b0   = blockIdx.x * NB;

    for (int i = tid; i < (int)(sizeof(hb) / 4); i += 256) ((int*)hb)[i] = 0;

    // ---- bias in registers: rows 32j + 16hf + 4g4 + (0..3) ----
    f32x4 bias[4];
    #pragma unroll
    for (int j = 0; j < 4; ++j) {
        const int rb = 32 * j + 16 * hf + 4 * g4;
        const float sc = L2E * ((j == 2) ? 2.0f : 1.0f);
        f32x4 bi, bh_;
        if (!isL2) { bi = *(const f32x4*)&bih0[rb]; bh_ = *(const f32x4*)&bhh0[rb]; }
        else       { bi = *(const f32x4*)&bih1[rb]; bh_ = *(const f32x4*)&bhh1[rb]; }
        bias[j] = (bi + bh_) * sc;
    }

    // ---- A-fragments, hi/lo split; this wave's M-tiles m = 2j + hf ----
    // row = 16m + b, k = 8*g4 + e within k-tile.
    // L1: kt0 = Whh0 (h1 recur), kt1 = Wih0 (x, k<10 else 0).
    // L2: kt0 = Wih1 (h1 input), kt1 = Whh1 (h2 recur).
    bf16x8 Ah[4][2], Al[4][2];
    #pragma unroll
    for (int j = 0; j < 4; ++j) {
        const int m = 2 * j + hf;
        const int row = 16 * m + b;
        const float sc = L2E * ((j == 2) ? 2.0f : 1.0f);
        #pragma unroll
        for (int kt = 0; kt < 2; ++kt) {
            bf16x8 hi, lo;
            #pragma unroll
            for (int e = 0; e < 8; ++e) {
                const int k = 8 * g4 + e;
                float w;
                if (!isL2) w = (kt == 0) ? Whh0[row * HH + k]
                                         : ((k < DD) ? Wih0[row * DD + k] : 0.0f);
                else       w = (kt == 0) ? Wih1[row * HH + k]
                                         : Whh1[row * HH + k];
                w *= sc;
                float rem;
                hi[e] = bfhi(w, rem);
                lo[e] = bfrd(rem);
            }
            Ah[j][kt] = hi;
            Al[j][kt] = lo;
        }
    }
    // empty pin: home A-frags in AGPRs (builtin MFMA reads AV-class natively;
    // correctness-free equivalent of r9's "a"-constraint intent)
    #pragma unroll
    for (int j = 0; j < 4; ++j) {
        asm volatile("" : "+a"(Ah[j][0]), "+a"(Ah[j][1]),
                          "+a"(Al[j][0]), "+a"(Al[j][1]));
    }

    float cst[4] = {0.f, 0.f, 0.f, 0.f};   // cell state, units 16hf+4g4+r
    __syncthreads();

#define STEP(KK, PR, DOL1, DOL2) do {                                          \
    const bool act_ = isL2 ? (DOL2) : (DOL1);                                  \
    if (act_) {                                                                \
        bf16x8 Bh1 = {0,0,0,0,0,0,0,0}, Bl1 = {0,0,0,0,0,0,0,0};               \
        if (!isL2) {                                                           \
            if (g4 < 2) {                                                      \
                const int tc_ = (KK) & (CH - 1);                               \
                Bh1 = *(const bf16x8*)&xh[b * XPS + tc_ * XRS + 8 * g4];       \
                Bl1 = *(const bf16x8*)&xl[b * XPS + tc_ * XRS + 8 * g4];       \
            }                                                                  \
        } else {                                                               \
            Bh1 = *(const bf16x8*)&hb[2][PR][b][8 * g4];                       \
            Bl1 = *(const bf16x8*)&hb[3][PR][b][8 * g4];                       \
        }                                                                      \
        bf16x8 Bh0 = *(const bf16x8*)&hb[0][(PR) ^ 1][b][8 * g4];              \
        bf16x8 Bl0 = *(const bf16x8*)&hb[1][(PR) ^ 1][b][8 * g4];              \
        f32x4 acc[4];                                                          \
        _Pragma("unroll")                                                      \
        for (int j = 0; j < 4; ++j) {                                          \
            f32x4 aA = bias[j];                                                \
            f32x4 aB = {0.f, 0.f, 0.f, 0.f};                                   \
            aA = __builtin_amdgcn_mfma_f32_16x16x32_bf16(Ah[j][0], Bh0, aA, 0, 0, 0); \
            aB = __builtin_amdgcn_mfma_f32_16x16x32_bf16(Ah[j][0], Bl0, aB, 0, 0, 0); \
            aA = __builtin_amdgcn_mfma_f32_16x16x32_bf16(Al[j][0], Bh0, aA, 0, 0, 0); \
            aB = __builtin_amdgcn_mfma_f32_16x16x32_bf16(Ah[j][1], Bh1, aB, 0, 0, 0); \
            aA = __builtin_amdgcn_mfma_f32_16x16x32_bf16(Ah[j][1], Bl1, aA, 0, 0, 0); \
            aB = __builtin_amdgcn_mfma_f32_16x16x32_bf16(Al[j][1], Bh1, aB, 0, 0, 0); \
            acc[j] = aA + aB;                                                  \
        }                                                                      \
        short hh_[4], hl_[4];                                                  \
        _Pragma("unroll")                                                      \
        for (int r = 0; r < 4; ++r) {                                          \
            const float iv = acc[0][r], fv = acc[1][r];                        \
            const float gv = acc[2][r], ov = acc[3][r];                        \
            const float gt = fmaf(2.0f, sig2(gv), -1.0f);                      \
            const float cn = fmaf(sig2(fv), cst[r], sig2(iv) * gt);            \
            cst[r] = cn;                                                       \
            const float h_ = sig2(ov) * fmaf(2.0f, sig2(2.0f * L2E * cn), -1.0f); \
            float rem_;                                                        \
            hh_[r] = bfhi(h_, rem_);                                           \
            hl_[r] = bfrd(rem_);                                               \
        }                                                                      \
        const int arr_ = isL2 ? 2 : 0;                                         \
        const int wp_  = isL2 ? ((PR) ^ 1) : (PR);                             \
        *(bf16x4*)&hb[arr_][wp_][b][16 * hf + 4 * g4]     =                    \
            bf16x4{hh_[0], hh_[1], hh_[2], hh_[3]};                            \
        *(bf16x4*)&hb[arr_ + 1][wp_][b][16 * hf + 4 * g4] =                    \
            bf16x4{hl_[0], hl_[1], hl_[2], hl_[3]};                            \
    }                                                                          \
    __syncthreads();                                                           \
} while (0)

    for (int ch = 0; ch < TT / CH; ++ch) {
        const int k0 = ch * CH;
        // ---- stage + pre-split x chunk (coalesced) ----
        #pragma unroll
        for (int p = 0; p < (CH * NB) / 256; ++p) {
            const int idx = tid + 256 * p;
            const int t = idx & (CH - 1), bb = idx >> 5;
            const f2* sp = (const f2*)(x + (size_t)(b0 + bb) * (TT * DD)
                                         + (size_t)(k0 + t) * DD);
            f2 v0 = sp[0], v1 = sp[1], v2 = sp[2], v3 = sp[3], v4 = sp[4];
            const float av[10] = {v0.x, v0.y, v1.x, v1.y, v2.x,
                                  v2.y, v3.x, v3.y, v4.x, v4.y};
            short th[16], tl[16];
            #pragma unroll
            for (int d = 0; d < DD; ++d) {
                float rem;
                th[d] = bfhi(av[d], rem);
                tl[d] = bfrd(rem);
            }
            #pragma unroll
            for (int d = DD; d < 16; ++d) { th[d] = 0; tl[d] = 0; }
            short* ph = &xh[bb * XPS + t * XRS];
            short* pl = &xl[bb * XPS + t * XRS];
            *(bf16x8*)(ph)     = bf16x8{th[0],th[1],th[2],th[3],th[4],th[5],th[6],th[7]};
            *(bf16x8*)(ph + 8) = bf16x8{th[8],th[9],th[10],th[11],th[12],th[13],th[14],th[15]};
            *(bf16x8*)(pl)     = bf16x8{tl[0],tl[1],tl[2],tl[3],tl[4],tl[5],tl[6],tl[7]};
            *(bf16x8*)(pl + 8) = bf16x8{tl[8],tl[9],tl[10],tl[11],tl[12],tl[13],tl[14],tl[15]};
        }
        __syncthreads();

        for (int t2 = 0; t2 < CH; t2 += 2) {
            const int kk = k0 + t2;
            STEP(kk,     0, true, kk > 0);
            STEP(kk + 1, 1, true, true);
        }
    }
    // drain: L2 computes timestep 511 at wavefront-iter 512 (parity 0)
    STEP(TT, 0, false, true);
#undef STEP

    // ---- final FC on h2(511): parity 1 -> hb[2/3][1] ----
    if (tid < NB) {
        float v = bfc[0];
        #pragma unroll
        for (int u = 0; u < HH; ++u) {
            const unsigned hi = (unsigned short)hb[2][1][tid][u];
            const unsigned lo = (unsigned short)hb[3][1][tid][u];
            const float h = __uint_as_float(hi << 16) + __uint_as_float(lo << 16);
            v = fmaf(h, Wfc[u], v);
        }
        out[b0 + tid] = v;
    }
}

extern "C" void kernel_launch(void* const* d_in, const int* in_sizes, int n_in,
                              void* d_out, int out_size, void* d_ws, size_t ws_size,
                              hipStream_t stream) {
    const float* x    = (const float*)d_in[0];
    const float* Wih0 = (const float*)d_in[1];
    const float* Whh0 = (const float*)d_in[2];
    const float* bih0 = (const float*)d_in[3];
    const float* bhh0 = (const float*)d_in[4];
    const float* Wih1 = (const float*)d_in[5];
    const float* Whh1 = (const float*)d_in[6];
    const float* bih1 = (const float*)d_in[7];
    const float* bhh1 = (const float*)d_in[8];
    const float* Wfc  = (const float*)d_in[9];
    const float* bfc  = (const float*)d_in[10];
    float* out = (float*)d_out;

    const int B = in_sizes[0] / (TT * DD);   // 4096
    dim3 grid(B / NB), block(256);           // 256 blocks x 4 waves
    hipLaunchKernelGGL(lstm2_r10, grid, block, 0, stream,
                       x, Wih0, Whh0, bih0, bhh0,
                       Wih1, Whh1, bih1, bhh1, Wfc, bfc, out);
}

// Round 12
// 427.283 us; speedup vs baseline: 4.4566x; 1.0272x over previous
//
#include <hip/hip_runtime.h>

// 2-layer LSTM (H=32, D=10, T=512), MFMA split-bf16, M-split 4-wave form.
// ROUND 11 = round-10 (PASSING, 439us) with:
//  * A-frags pinned "+v" (def + per-step-pair re-pin). launch_bounds(256,1)
//    gives a 512-VGPR budget -> resident frags cost nothing; kills the
//    v_accvgpr shuttle junk (r10: "+a" pin self-inflicted AGPR parking).
//  * MFMA chains regrouped by barrier-dependency: aB = x/h2 tile (ready
//    early), aA = h1 tile (post-barrier) -> shorter critical path.
//  * L1 x-fragment prefetched BEFORE the barrier (chunk data static) ->
//    3 MFMAs issue immediately post-barrier while h1 ds_reads fly.
//  * Branchless zero-row for L1 lanes g4>=2 (no divergent exec juggling).
// wave0/1 = L1 unit-halves (step k), wave2/3 = L2 unit-halves (step k-1).
// 3-term split (AhBh+AhBl+AlBh) = fp32-accurate (r8/r10: absmax 2.4e-4).

#define HH 32
#define DD 10
#define TT 512
#define CH 32              // x timesteps staged per chunk
#define NB 16              // batches per block
#define XPS 776            // x plane stride per batch (shorts)
#define XRS 24             // x row stride per timestep (shorts)
#define RS  40             // h row stride per batch (shorts)
#define ZOFF (NB * XPS)    // zero-row offset (16 shorts)
#define L2E 1.44269504088896340736f

typedef __attribute__((ext_vector_type(4))) float f32x4;
typedef __attribute__((ext_vector_type(8))) short bf16x8;
typedef __attribute__((ext_vector_type(4))) short bf16x4;
typedef __attribute__((ext_vector_type(2))) float f2;

__device__ __forceinline__ short bfhi(float x, float& rem) {
    unsigned u = __float_as_uint(x);
    unsigned short h = (unsigned short)((u + 0x8000u) >> 16);
    rem = x - __uint_as_float(((unsigned)h) << 16);   // exact residual
    return (short)h;
}
__device__ __forceinline__ short bfrd(float x) {
    return (short)(unsigned short)((__float_as_uint(x) + 0x8000u) >> 16);
}
__device__ __forceinline__ float sig2(float v) {   // 1/(1+2^-v), v pre-scaled
    return __builtin_amdgcn_rcpf(1.0f + exp2f(-v));
}
__device__ __forceinline__ f32x4 mfma16(const bf16x8 a, const bf16x8 b, f32x4 c) {
    return __builtin_amdgcn_mfma_f32_16x16x32_bf16(a, b, c, 0, 0, 0);
}

__global__ __launch_bounds__(256, 1) void lstm2_r11(
    const float* __restrict__ x,
    const float* __restrict__ Wih0, const float* __restrict__ Whh0,
    const float* __restrict__ bih0, const float* __restrict__ bhh0,
    const float* __restrict__ Wih1, const float* __restrict__ Whh1,
    const float* __restrict__ bih1, const float* __restrict__ bhh1,
    const float* __restrict__ Wfc,  const float* __restrict__ bfc,
    float* __restrict__ out)
{
    __shared__ __align__(16) short xh[NB * XPS + 16]; // 24.9 KB  x hi + zero row
    __shared__ __align__(16) short xl[NB * XPS + 16]; // 24.9 KB  x lo + zero row
    __shared__ __align__(16) short hb[4][2][NB][RS];  // 10 KB: h1h,h1l,h2h,h2l

    const int tid  = threadIdx.x;
    const int wid  = tid >> 6;       // 0,1 = L1 halves; 2,3 = L2 halves
    const bool isL2 = wid >= 2;
    const int hf   = wid & 1;        // unit half: 0 -> units 0-15, 1 -> 16-31
    const int lane = tid & 63;
    const int b    = lane & 15;      // batch col (B/D) / row-local (A)
    const int g4   = lane >> 4;      // k-slot group
    const int b0   = blockIdx.x * NB;

    for (int i = tid; i < (int)(sizeof(hb) / 4); i += 256) ((int*)hb)[i] = 0;
    if (tid < 16) { xh[ZOFF + tid] = 0; xl[ZOFF + tid] = 0; }

    // ---- bias in registers: rows 32j + 16hf + 4g4 + (0..3) ----
    f32x4 bias[4];
    #pragma unroll
    for (int j = 0; j < 4; ++j) {
        const int rb = 32 * j + 16 * hf + 4 * g4;
        const float sc = L2E * ((j == 2) ? 2.0f : 1.0f);
        f32x4 bi, bh_;
        if (!isL2) { bi = *(const f32x4*)&bih0[rb]; bh_ = *(const f32x4*)&bhh0[rb]; }
        else       { bi = *(const f32x4*)&bih1[rb]; bh_ = *(const f32x4*)&bhh1[rb]; }
        bias[j] = (bi + bh_) * sc;
    }

    // ---- A-fragments, hi/lo split; this wave's M-tiles m = 2j + hf ----
    // row = 16m + b, k = 8*g4 + e within k-tile.
    // L1: kt0 = Whh0 (h1 recur), kt1 = Wih0 (x, k<10 else 0).
    // L2: kt0 = Wih1 (h1 input), kt1 = Whh1 (h2 recur).
    bf16x8 Ah[4][2], Al[4][2];
    #pragma unroll
    for (int j = 0; j < 4; ++j) {
        const int m = 2 * j + hf;
        const int row = 16 * m + b;
        const float sc = L2E * ((j == 2) ? 2.0f : 1.0f);
        #pragma unroll
        for (int kt = 0; kt < 2; ++kt) {
            bf16x8 hi, lo;
            #pragma unroll
            for (int e = 0; e < 8; ++e) {
                const int k = 8 * g4 + e;
                float w;
                if (!isL2) w = (kt == 0) ? Whh0[row * HH + k]
                                         : ((k < DD) ? Wih0[row * DD + k] : 0.0f);
                else       w = (kt == 0) ? Wih1[row * HH + k]
                                         : Whh1[row * HH + k];
                w *= sc;
                float rem;
                hi[e] = bfhi(w, rem);
                lo[e] = bfrd(rem);
            }
            Ah[j][kt] = hi;
            Al[j][kt] = lo;
        }
    }
    // pin fragments into VGPRs (512-reg budget at 1 wave/SIMD: no pressure)
    #pragma unroll
    for (int j = 0; j < 4; ++j) {
        asm volatile("" : "+v"(Ah[j][0]), "+v"(Ah[j][1]),
                          "+v"(Al[j][0]), "+v"(Al[j][1]));
    }

    float cst[4] = {0.f, 0.f, 0.f, 0.f};   // cell state, units 16hf+4g4+r
    bf16x8 pXh, pXl;                        // L1 x-frag prefetch registers
    __syncthreads();

#define STEP(KK, PR, DOL1, DOL2, XIN, XOUT) do {                               \
    const bool act_ = isL2 ? (DOL2) : (DOL1);                                  \
    if (act_) {                                                                \
        bf16x8 Bh0, Bl0, Bh1, Bl1;                                             \
        if (!isL2) {                                                           \
            if (XIN) { Bh1 = pXh; Bl1 = pXl; }                                 \
            else {                                                             \
                const int tc0_ = (KK) & (CH - 1);                              \
                const int xo_ = (g4 < 2) ? (b * XPS + tc0_ * XRS + 8 * g4)     \
                                         : ZOFF;                               \
                Bh1 = *(const bf16x8*)&xh[xo_];                                \
                Bl1 = *(const bf16x8*)&xl[xo_];                                \
            }                                                                  \
        } else {                                                               \
            Bh1 = *(const bf16x8*)&hb[2][PR][b][8 * g4];                       \
            Bl1 = *(const bf16x8*)&hb[3][PR][b][8 * g4];                       \
        }                                                                      \
        Bh0 = *(const bf16x8*)&hb[0][(PR) ^ 1][b][8 * g4];                     \
        Bl0 = *(const bf16x8*)&hb[1][(PR) ^ 1][b][8 * g4];                     \
        f32x4 acc[4];                                                          \
        _Pragma("unroll")                                                      \
        for (int j = 0; j < 4; ++j) {                                          \
            f32x4 aB = {0.f, 0.f, 0.f, 0.f};      /* barrier-independent */    \
            aB = mfma16(Ah[j][1], Bh1, aB);                                    \
            aB = mfma16(Al[j][1], Bh1, aB);                                    \
            aB = mfma16(Ah[j][1], Bl1, aB);                                    \
            f32x4 aA = bias[j];                    /* h1-dependent */          \
            aA = mfma16(Ah[j][0], Bh0, aA);                                    \
            aA = mfma16(Al[j][0], Bh0, aA);                                    \
            aA = mfma16(Ah[j][0], Bl0, aA);                                    \
            acc[j] = aA + aB;                                                  \
        }                                                                      \
        short hh_[4], hl_[4];                                                  \
        _Pragma("unroll")                                                      \
        for (int r = 0; r < 4; ++r) {                                          \
            const float iv = acc[0][r], fv = acc[1][r];                        \
            const float gv = acc[2][r], ov = acc[3][r];                        \
            const float gt = fmaf(2.0f, sig2(gv), -1.0f);                      \
            const float cn = fmaf(sig2(fv), cst[r], sig2(iv) * gt);            \
            cst[r] = cn;                                                       \
            const float h_ = sig2(ov) * fmaf(2.0f, sig2(2.0f * L2E * cn), -1.0f); \
            float rem_;                                                        \
            hh_[r] = bfhi(h_, rem_);                                           \
            hl_[r] = bfrd(rem_);                                               \
        }                                                                      \
        const int arr_ = isL2 ? 2 : 0;                                         \
        const int wp_  = isL2 ? ((PR) ^ 1) : (PR);                             \
        *(bf16x4*)&hb[arr_][wp_][b][16 * hf + 4 * g4]     =                    \
            bf16x4{hh_[0], hh_[1], hh_[2], hh_[3]};                            \
        *(bf16x4*)&hb[arr_ + 1][wp_][b][16 * hf + 4 * g4] =                    \
            bf16x4{hl_[0], hl_[1], hl_[2], hl_[3]};                            \
    }                                                                          \
    if (!isL2 && (XOUT)) {          /* cross-barrier x prefetch for KK+1 */    \
        const int tcn_ = ((KK) + 1) & (CH - 1);                                \
        const int xo_ = (g4 < 2) ? (b * XPS + tcn_ * XRS + 8 * g4) : ZOFF;     \
        pXh = *(const bf16x8*)&xh[xo_];                                        \
        pXl = *(const bf16x8*)&xl[xo_];                                        \
    }                                                                          \
    __syncthreads();                                                           \
} while (0)

    for (int ch = 0; ch < TT / CH; ++ch) {
        const int k0 = ch * CH;
        // ---- stage + pre-split x chunk (coalesced) ----
        #pragma unroll
        for (int p = 0; p < (CH * NB) / 256; ++p) {
            const int idx = tid + 256 * p;
            const int t = idx & (CH - 1), bb = idx >> 5;
            const f2* sp = (const f2*)(x + (size_t)(b0 + bb) * (TT * DD)
                                         + (size_t)(k0 + t) * DD);
            f2 v0 = sp[0], v1 = sp[1], v2 = sp[2], v3 = sp[3], v4 = sp[4];
            const float av[10] = {v0.x, v0.y, v1.x, v1.y, v2.x,
                                  v2.y, v3.x, v3.y, v4.x, v4.y};
            short th[16], tl[16];
            #pragma unroll
            for (int d = 0; d < DD; ++d) {
                float rem;
                th[d] = bfhi(av[d], rem);
                tl[d] = bfrd(rem);
            }
            #pragma unroll
            for (int d = DD; d < 16; ++d) { th[d] = 0; tl[d] = 0; }
            short* ph = &xh[bb * XPS + t * XRS];
            short* pl = &xl[bb * XPS + t * XRS];
            *(bf16x8*)(ph)     = bf16x8{th[0],th[1],th[2],th[3],th[4],th[5],th[6],th[7]};
            *(bf16x8*)(ph + 8) = bf16x8{th[8],th[9],th[10],th[11],th[12],th[13],th[14],th[15]};
            *(bf16x8*)(pl)     = bf16x8{tl[0],tl[1],tl[2],tl[3],tl[4],tl[5],tl[6],tl[7]};
            *(bf16x8*)(pl + 8) = bf16x8{tl[8],tl[9],tl[10],tl[11],tl[12],tl[13],tl[14],tl[15]};
        }
        __syncthreads();

        for (int t2 = 0; t2 < CH; t2 += 2) {
            const int kk = k0 + t2;
            // re-pin A-frags once per step pair (costless if VGPR-resident)
            #pragma unroll
            for (int j = 0; j < 4; ++j) {
                asm volatile("" : "+v"(Ah[j][0]), "+v"(Ah[j][1]),
                                  "+v"(Al[j][0]), "+v"(Al[j][1]));
            }
            const bool xin0  = (t2 != 0);
            const bool xoutB = (t2 + 2 < CH);
            STEP(kk,     0, true, kk > 0, xin0, true);
            STEP(kk + 1, 1, true, true,   true, xoutB);
        }
    }
    // drain: L2 computes timestep 511 at wavefront-iter 512 (parity 0)
    STEP(TT, 0, false, true, false, false);
#undef STEP

    // ---- final FC on h2(511): parity 1 -> hb[2/3][1] ----
    if (tid < NB) {
        float v = bfc[0];
        #pragma unroll
        for (int u = 0; u < HH; ++u) {
            const unsigned hi = (unsigned short)hb[2][1][tid][u];
            const unsigned lo = (unsigned short)hb[3][1][tid][u];
            const float h = __uint_as_float(hi << 16) + __uint_as_float(lo << 16);
            v = fmaf(h, Wfc[u], v);
        }
        out[b0 + tid] = v;
    }
}

extern "C" void kernel_launch(void* const* d_in, const int* in_sizes, int n_in,
                              void* d_out, int out_size, void* d_ws, size_t ws_size,
                              hipStream_t stream) {
    const float* x    = (const float*)d_in[0];
    const float* Wih0 = (const float*)d_in[1];
    const float* Whh0 = (const float*)d_in[2];
    const float* bih0 = (const float*)d_in[3];
    const float* bhh0 = (const float*)d_in[4];
    const float* Wih1 = (const float*)d_in[5];
    const float* Whh1 = (const float*)d_in[6];
    const float* bih1 = (const float*)d_in[7];
    const float* bhh1 = (const float*)d_in[8];
    const float* Wfc  = (const float*)d_in[9];
    const float* bfc  = (const float*)d_in[10];
    float* out = (float*)d_out;

    const int B = in_sizes[0] / (TT * DD);   // 4096
    dim3 grid(B / NB), block(256);           // 256 blocks x 4 waves
    hipLaunchKernelGGL(lstm2_r11, grid, block, 0, stream,
                       x, Wih0, Whh0, bih0, bhh0,
                       Wih1, Whh1, bih1, bhh1, Wfc, bfc, out);
}

// Round 13
// 421.842 us; speedup vs baseline: 4.5141x; 1.0129x over previous
//
#include <hip/hip_runtime.h>

// 2-layer LSTM (H=32, D=10, T=512), MFMA split-bf16, M-split 4-wave form.
// ROUND 12 = round-11 (PASSING, 427us, frags VGPR-resident) with a
// SHARED-RECIPROCAL activation: the 4 gate sigmoids of a unit share ONE
// v_rcp_f32 (R = 1/(d1 d2 d3 d4), sigma_i = R * P/d_i via prefix/suffix
// products). Per unit: 5 exp + 2 rcp (was 5+5). Transcendentals were the
// largest issue term (40 instr/step/wave at quarter rate ~640cyc).
// Overflow-safe: P <= 2^98 for |gate preact| <= 13.5 (bounded h, weights).
// wave0/1 = L1 unit-halves (step k), wave2/3 = L2 unit-halves (step k-1).
// 3-term split (AhBh+AhBl+AlBh) = fp32-accurate (r8/r10/r11: absmax 2.4e-4).

#define HH 32
#define DD 10
#define TT 512
#define CH 32              // x timesteps staged per chunk
#define NB 16              // batches per block
#define XPS 776            // x plane stride per batch (shorts)
#define XRS 24             // x row stride per timestep (shorts)
#define RS  40             // h row stride per batch (shorts)
#define ZOFF (NB * XPS)    // zero-row offset (16 shorts)
#define L2E 1.44269504088896340736f

typedef __attribute__((ext_vector_type(4))) float f32x4;
typedef __attribute__((ext_vector_type(8))) short bf16x8;
typedef __attribute__((ext_vector_type(4))) short bf16x4;
typedef __attribute__((ext_vector_type(2))) float f2;

__device__ __forceinline__ short bfhi(float x, float& rem) {
    unsigned u = __float_as_uint(x);
    unsigned short h = (unsigned short)((u + 0x8000u) >> 16);
    rem = x - __uint_as_float(((unsigned)h) << 16);   // exact residual
    return (short)h;
}
__device__ __forceinline__ short bfrd(float x) {
    return (short)(unsigned short)((__float_as_uint(x) + 0x8000u) >> 16);
}
__device__ __forceinline__ f32x4 mfma16(const bf16x8 a, const bf16x8 b, f32x4 c) {
    return __builtin_amdgcn_mfma_f32_16x16x32_bf16(a, b, c, 0, 0, 0);
}

__global__ __launch_bounds__(256, 1) void lstm2_r12(
    const float* __restrict__ x,
    const float* __restrict__ Wih0, const float* __restrict__ Whh0,
    const float* __restrict__ bih0, const float* __restrict__ bhh0,
    const float* __restrict__ Wih1, const float* __restrict__ Whh1,
    const float* __restrict__ bih1, const float* __restrict__ bhh1,
    const float* __restrict__ Wfc,  const float* __restrict__ bfc,
    float* __restrict__ out)
{
    __shared__ __align__(16) short xh[NB * XPS + 16]; // 24.9 KB  x hi + zero row
    __shared__ __align__(16) short xl[NB * XPS + 16]; // 24.9 KB  x lo + zero row
    __shared__ __align__(16) short hb[4][2][NB][RS];  // 10 KB: h1h,h1l,h2h,h2l

    const int tid  = threadIdx.x;
    const int wid  = tid >> 6;       // 0,1 = L1 halves; 2,3 = L2 halves
    const bool isL2 = wid >= 2;
    const int hf   = wid & 1;        // unit half: 0 -> units 0-15, 1 -> 16-31
    const int lane = tid & 63;
    const int b    = lane & 15;      // batch col (B/D) / row-local (A)
    const int g4   = lane >> 4;      // k-slot group
    const int b0   = blockIdx.x * NB;

    for (int i = tid; i < (int)(sizeof(hb) / 4); i += 256) ((int*)hb)[i] = 0;
    if (tid < 16) { xh[ZOFF + tid] = 0; xl[ZOFF + tid] = 0; }

    // ---- bias in registers: rows 32j + 16hf + 4g4 + (0..3) ----
    f32x4 bias[4];
    #pragma unroll
    for (int j = 0; j < 4; ++j) {
        const int rb = 32 * j + 16 * hf + 4 * g4;
        const float sc = L2E * ((j == 2) ? 2.0f : 1.0f);
        f32x4 bi, bh_;
        if (!isL2) { bi = *(const f32x4*)&bih0[rb]; bh_ = *(const f32x4*)&bhh0[rb]; }
        else       { bi = *(const f32x4*)&bih1[rb]; bh_ = *(const f32x4*)&bhh1[rb]; }
        bias[j] = (bi + bh_) * sc;
    }

    // ---- A-fragments, hi/lo split; this wave's M-tiles m = 2j + hf ----
    bf16x8 Ah[4][2], Al[4][2];
    #pragma unroll
    for (int j = 0; j < 4; ++j) {
        const int m = 2 * j + hf;
        const int row = 16 * m + b;
        const float sc = L2E * ((j == 2) ? 2.0f : 1.0f);
        #pragma unroll
        for (int kt = 0; kt < 2; ++kt) {
            bf16x8 hi, lo;
            #pragma unroll
            for (int e = 0; e < 8; ++e) {
                const int k = 8 * g4 + e;
                float w;
                if (!isL2) w = (kt == 0) ? Whh0[row * HH + k]
                                         : ((k < DD) ? Wih0[row * DD + k] : 0.0f);
                else       w = (kt == 0) ? Wih1[row * HH + k]
                                         : Whh1[row * HH + k];
                w *= sc;
                float rem;
                hi[e] = bfhi(w, rem);
                lo[e] = bfrd(rem);
            }
            Ah[j][kt] = hi;
            Al[j][kt] = lo;
        }
    }
    // pin fragments into VGPRs (512-reg budget at 1 wave/SIMD)
    #pragma unroll
    for (int j = 0; j < 4; ++j) {
        asm volatile("" : "+v"(Ah[j][0]), "+v"(Ah[j][1]),
                          "+v"(Al[j][0]), "+v"(Al[j][1]));
    }

    float cst[4] = {0.f, 0.f, 0.f, 0.f};   // cell state, units 16hf+4g4+r
    bf16x8 pXh, pXl;                        // L1 x-frag prefetch registers
    __syncthreads();

#define STEP(KK, PR, DOL1, DOL2, XIN, XOUT) do {                               \
    const bool act_ = isL2 ? (DOL2) : (DOL1);                                  \
    if (act_) {                                                                \
        bf16x8 Bh0, Bl0, Bh1, Bl1;                                             \
        if (!isL2) {                                                           \
            if (XIN) { Bh1 = pXh; Bl1 = pXl; }                                 \
            else {                                                             \
                const int tc0_ = (KK) & (CH - 1);                              \
                const int xo_ = (g4 < 2) ? (b * XPS + tc0_ * XRS + 8 * g4)     \
                                         : ZOFF;                               \
                Bh1 = *(const bf16x8*)&xh[xo_];                                \
                Bl1 = *(const bf16x8*)&xl[xo_];                                \
            }                                                                  \
        } else {                                                               \
            Bh1 = *(const bf16x8*)&hb[2][PR][b][8 * g4];                       \
            Bl1 = *(const bf16x8*)&hb[3][PR][b][8 * g4];                       \
        }                                                                      \
        Bh0 = *(const bf16x8*)&hb[0][(PR) ^ 1][b][8 * g4];                     \
        Bl0 = *(const bf16x8*)&hb[1][(PR) ^ 1][b][8 * g4];                     \
        f32x4 acc[4];                                                          \
        _Pragma("unroll")                                                      \
        for (int j = 0; j < 4; ++j) {                                          \
            f32x4 aB = {0.f, 0.f, 0.f, 0.f};      /* barrier-independent */    \
            aB = mfma16(Ah[j][1], Bh1, aB);                                    \
            aB = mfma16(Al[j][1], Bh1, aB);                                    \
            aB = mfma16(Ah[j][1], Bl1, aB);                                    \
            f32x4 aA = bias[j];                    /* h1-dependent */          \
            aA = mfma16(Ah[j][0], Bh0, aA);                                    \
            aA = mfma16(Al[j][0], Bh0, aA);                                    \
            aA = mfma16(Ah[j][0], Bl0, aA);                                    \
            acc[j] = aA + aB;                                                  \
        }                                                                      \
        short hh_[4], hl_[4];                                                  \
        _Pragma("unroll")                                                      \
        for (int r = 0; r < 4; ++r) {                                          \
            /* shared-reciprocal activation: one rcp for 4 gate sigmoids */    \
            const float e1 = exp2f(-acc[0][r]);   /* i */                      \
            const float e2 = exp2f(-acc[1][r]);   /* f */                      \
            const float e3 = exp2f(-acc[2][r]);   /* g (pre-scaled 2*L2E) */   \
            const float e4 = exp2f(-acc[3][r]);   /* o */                      \
            const float d1 = 1.0f + e1, d2 = 1.0f + e2;                        \
            const float d3 = 1.0f + e3, d4 = 1.0f + e4;                        \
            const float p12  = d1 * d2;                                        \
            const float p123 = p12 * d3;                                       \
            const float s34  = d3 * d4;                                        \
            const float s234 = d2 * s34;                                       \
            const float t3   = p12 * d4;                                       \
            const float R  = __builtin_amdgcn_rcpf(p123 * d4);                 \
            const float si = R * s234;            /* sigmoid(i) */             \
            const float sf = (R * d1) * s34;      /* sigmoid(f) */             \
            const float so = R * p123;            /* sigmoid(o) */             \
            const float tg = fmaf(2.0f * R, t3, -1.0f);   /* tanh(g) */        \
            const float cn = fmaf(sf, cst[r], si * tg);                        \
            cst[r] = cn;                                                       \
            const float ec = exp2f(-2.0f * L2E * cn);                          \
            const float tc = fmaf(2.0f,                                        \
                __builtin_amdgcn_rcpf(1.0f + ec), -1.0f);     /* tanh(c) */    \
            const float h_ = so * tc;                                          \
            float rem_;                                                        \
            hh_[r] = bfhi(h_, rem_);                                           \
            hl_[r] = bfrd(rem_);                                               \
        }                                                                      \
        const int arr_ = isL2 ? 2 : 0;                                         \
        const int wp_  = isL2 ? ((PR) ^ 1) : (PR);                             \
        *(bf16x4*)&hb[arr_][wp_][b][16 * hf + 4 * g4]     =                    \
            bf16x4{hh_[0], hh_[1], hh_[2], hh_[3]};                            \
        *(bf16x4*)&hb[arr_ + 1][wp_][b][16 * hf + 4 * g4] =                    \
            bf16x4{hl_[0], hl_[1], hl_[2], hl_[3]};                            \
    }                                                                          \
    if (!isL2 && (XOUT)) {          /* cross-barrier x prefetch for KK+1 */    \
        const int tcn_ = ((KK) + 1) & (CH - 1);                                \
        const int xo_ = (g4 < 2) ? (b * XPS + tcn_ * XRS + 8 * g4) : ZOFF;     \
        pXh = *(const bf16x8*)&xh[xo_];                                        \
        pXl = *(const bf16x8*)&xl[xo_];                                        \
    }                                                                          \
    __syncthreads();                                                           \
} while (0)

    for (int ch = 0; ch < TT / CH; ++ch) {
        const int k0 = ch * CH;
        // ---- stage + pre-split x chunk (coalesced) ----
        #pragma unroll
        for (int p = 0; p < (CH * NB) / 256; ++p) {
            const int idx = tid + 256 * p;
            const int t = idx & (CH - 1), bb = idx >> 5;
            const f2* sp = (const f2*)(x + (size_t)(b0 + bb) * (TT * DD)
                                         + (size_t)(k0 + t) * DD);
            f2 v0 = sp[0], v1 = sp[1], v2 = sp[2], v3 = sp[3], v4 = sp[4];
            const float av[10] = {v0.x, v0.y, v1.x, v1.y, v2.x,
                                  v2.y, v3.x, v3.y, v4.x, v4.y};
            short th[16], tl[16];
            #pragma unroll
            for (int d = 0; d < DD; ++d) {
                float rem;
                th[d] = bfhi(av[d], rem);
                tl[d] = bfrd(rem);
            }
            #pragma unroll
            for (int d = DD; d < 16; ++d) { th[d] = 0; tl[d] = 0; }
            short* ph = &xh[bb * XPS + t * XRS];
            short* pl = &xl[bb * XPS + t * XRS];
            *(bf16x8*)(ph)     = bf16x8{th[0],th[1],th[2],th[3],th[4],th[5],th[6],th[7]};
            *(bf16x8*)(ph + 8) = bf16x8{th[8],th[9],th[10],th[11],th[12],th[13],th[14],th[15]};
            *(bf16x8*)(pl)     = bf16x8{tl[0],tl[1],tl[2],tl[3],tl[4],tl[5],tl[6],tl[7]};
            *(bf16x8*)(pl + 8) = bf16x8{tl[8],tl[9],tl[10],tl[11],tl[12],tl[13],tl[14],tl[15]};
        }
        __syncthreads();

        for (int t2 = 0; t2 < CH; t2 += 2) {
            const int kk = k0 + t2;
            // re-pin A-frags once per step pair (costless if VGPR-resident)
            #pragma unroll
            for (int j = 0; j < 4; ++j) {
                asm volatile("" : "+v"(Ah[j][0]), "+v"(Ah[j][1]),
                                  "+v"(Al[j][0]), "+v"(Al[j][1]));
            }
            const bool xin0  = (t2 != 0);
            const bool xoutB = (t2 + 2 < CH);
            STEP(kk,     0, true, kk > 0, xin0, true);
            STEP(kk + 1, 1, true, true,   true, xoutB);
        }
    }
    // drain: L2 computes timestep 511 at wavefront-iter 512 (parity 0)
    STEP(TT, 0, false, true, false, false);
#undef STEP

    // ---- final FC on h2(511): parity 1 -> hb[2/3][1] ----
    if (tid < NB) {
        float v = bfc[0];
        #pragma unroll
        for (int u = 0; u < HH; ++u) {
            const unsigned hi = (unsigned short)hb[2][1][tid][u];
            const unsigned lo = (unsigned short)hb[3][1][tid][u];
            const float h = __uint_as_float(hi << 16) + __uint_as_float(lo << 16);
            v = fmaf(h, Wfc[u], v);
        }
        out[b0 + tid] = v;
    }
}

extern "C" void kernel_launch(void* const* d_in, const int* in_sizes, int n_in,
                              void* d_out, int out_size, void* d_ws, size_t ws_size,
                              hipStream_t stream) {
    const float* x    = (const float*)d_in[0];
    const float* Wih0 = (const float*)d_in[1];
    const float* Whh0 = (const float*)d_in[2];
    const float* bih0 = (const float*)d_in[3];
    const float* bhh0 = (const float*)d_in[4];
    const float* Wih1 = (const float*)d_in[5];
    const float* Whh1 = (const float*)d_in[6];
    const float* bih1 = (const float*)d_in[7];
    const float* bhh1 = (const float*)d_in[8];
    const float* Wfc  = (const float*)d_in[9];
    const float* bfc  = (const float*)d_in[10];
    float* out = (float*)d_out;

    const int B = in_sizes[0] / (TT * DD);   // 4096
    dim3 grid(B / NB), block(256);           // 256 blocks x 4 waves
    hipLaunchKernelGGL(lstm2_r12, grid, block, 0, stream,
                       x, Wih0, Whh0, bih0, bhh0,
                       Wih1, Whh1, bih1, bhh1, Wfc, bfc, out);
}